// Round 7
// baseline (695.726 us; speedup 1.0000x reference)
//
#include <hip/hip_runtime.h>

#define B_   4
#define T_   2048
#define C_   1024
#define QD   256
#define KVD  32
#define NR   (B_*T_)          // 8192 rows
#define EPSF 1e-5f
#define CAPS 64.0f
#define INV_SS (1.0f/1024.0f)

typedef __attribute__((ext_vector_type(8))) short bf16x8;
typedef __attribute__((ext_vector_type(4))) short bf16x4;
typedef __attribute__((ext_vector_type(4))) float f32x4;

// ---------- dtype helpers (runtime-flagged) ----------
__device__ __forceinline__ float bf2f(unsigned short h) {
    return __uint_as_float(((unsigned)h) << 16);
}
__device__ __forceinline__ unsigned short f2bf(float f) {
    unsigned u = __float_as_uint(f);
    u = u + 0x7fffu + ((u >> 16) & 1u);   // round-to-nearest-even
    return (unsigned short)(u >> 16);
}
__device__ __forceinline__ float ldf(const void* p, long i, int isbf) {
    return isbf ? bf2f(((const unsigned short*)p)[i]) : ((const float*)p)[i];
}
__device__ __forceinline__ long ldix(const void* p, long i, int is64) {
    return is64 ? (long)((const long long*)p)[i] : (long)((const int*)p)[i];
}
__device__ __forceinline__ float fast_tanh(float v) {
    float u = __expf(2.0f * v);          // overflow->inf->th=1; underflow->0->th=-1
    return 1.0f - 2.0f / (u + 1.0f);
}

// ---------- dtype detection ----------
__global__ void detect_kernel(const void* x, const void* idxp, int* flags) {
    __shared__ int cnt[2];
    int tid = threadIdx.x;
    if (tid < 2) cnt[tid] = 0;
    __syncthreads();
    int pl = 0;
    const unsigned short* u = (const unsigned short*)x;
    for (int r = 0; r < 2; r++) {
        long j = 2L * (((long)(tid * 2 + r) * 15013L) % 4000000L);
        unsigned short v = u[j];
        int e = (v >> 7) & 0xff;
        pl += (v == 0 || (e >= 100 && e <= 140)) ? 1 : 0;
    }
    atomicAdd(&cnt[0], pl);
    const unsigned* w = (const unsigned*)idxp;
    int z = (w[2 * tid + 1] == 0u) ? 1 : 0;
    atomicAdd(&cnt[1], z);
    __syncthreads();
    if (tid == 0) {
        flags[0] = (cnt[0] > 384) ? 1 : 0;   // float tensors are bf16
        flags[1] = (cnt[1] > 128) ? 1 : 0;   // idx is int64
    }
}

// ---------- zero the attention output (atomic-accumulate target) ----------
__global__ __launch_bounds__(256) void zero_kernel(float* __restrict__ out) {
    const long i = ((long)blockIdx.x * 256 + threadIdx.x) * 4;
    *reinterpret_cast<float4*>(out + i) = (float4){0.f, 0.f, 0.f, 0.f};
}

// ---------- tiled GEMM: C[M,N] = act(A[M,K] @ W[N,K]^T) (* emb gather) ----------
template<int BN, int TANH, int EMB>
__global__ __launch_bounds__(256) void gemm_kernel(
    const void* __restrict__ A, const void* __restrict__ W,
    const void* __restrict__ emb, const void* __restrict__ idxp,
    float* __restrict__ Cout, int M, int K, int N, int embN, int amode,
    const int* __restrict__ flags, int lda)
{
    const int fbf = flags[0];
    const int abf = amode ? fbf : 0;
    const int i64 = flags[1];

    __shared__ float As[32][68];
    __shared__ float Bs[32][BN + 4];

    const int tid = threadIdx.x;
    const long m0 = (long)blockIdx.x * 64;
    const int  n0 = blockIdx.y * BN;
    constexpr int TN = (BN == 64) ? 4 : 2;
    const int tx = tid & 15;
    const int ty = tid >> 4;

    float c[4][TN];
#pragma unroll
    for (int i = 0; i < 4; i++)
#pragma unroll
        for (int j = 0; j < TN; j++) c[i][j] = 0.0f;

    for (int k0 = 0; k0 < K; k0 += 32) {
        {
            int i = tid >> 2;
            int j0 = (tid & 3) * 8;
            long base = (m0 + i) * (long)lda + k0 + j0;
            if (abf) {
                bf16x8 av = *reinterpret_cast<const bf16x8*>((const unsigned short*)A + base);
#pragma unroll
                for (int jj = 0; jj < 8; jj++) As[j0 + jj][i] = bf2f((unsigned short)av[jj]);
            } else {
                const float4* ap = reinterpret_cast<const float4*>((const float*)A + base);
                float4 f0 = ap[0], f1 = ap[1];
                As[j0 + 0][i] = f0.x; As[j0 + 1][i] = f0.y;
                As[j0 + 2][i] = f0.z; As[j0 + 3][i] = f0.w;
                As[j0 + 4][i] = f1.x; As[j0 + 5][i] = f1.y;
                As[j0 + 6][i] = f1.z; As[j0 + 7][i] = f1.w;
            }
        }
        if (BN == 64) {
            int n = tid >> 2;
            int j0 = (tid & 3) * 8;
            long base = (long)(n0 + n) * K + k0 + j0;
            if (fbf) {
                bf16x8 bv = *reinterpret_cast<const bf16x8*>((const unsigned short*)W + base);
#pragma unroll
                for (int jj = 0; jj < 8; jj++) Bs[j0 + jj][n] = bf2f((unsigned short)bv[jj]);
            } else {
                const float4* bp = reinterpret_cast<const float4*>((const float*)W + base);
                float4 f0 = bp[0], f1 = bp[1];
                Bs[j0 + 0][n] = f0.x; Bs[j0 + 1][n] = f0.y;
                Bs[j0 + 2][n] = f0.z; Bs[j0 + 3][n] = f0.w;
                Bs[j0 + 4][n] = f1.x; Bs[j0 + 5][n] = f1.y;
                Bs[j0 + 6][n] = f1.z; Bs[j0 + 7][n] = f1.w;
            }
        } else {
            int n = tid >> 3;
            int j0 = (tid & 7) * 4;
            long base = (long)(n0 + n) * K + k0 + j0;
            if (fbf) {
                bf16x4 bv = *reinterpret_cast<const bf16x4*>((const unsigned short*)W + base);
#pragma unroll
                for (int jj = 0; jj < 4; jj++) Bs[j0 + jj][n] = bf2f((unsigned short)bv[jj]);
            } else {
                float4 f0 = *reinterpret_cast<const float4*>((const float*)W + base);
                Bs[j0 + 0][n] = f0.x; Bs[j0 + 1][n] = f0.y;
                Bs[j0 + 2][n] = f0.z; Bs[j0 + 3][n] = f0.w;
            }
        }
        __syncthreads();
#pragma unroll
        for (int kk = 0; kk < 32; kk++) {
            const float4 af = *reinterpret_cast<const float4*>(&As[kk][ty * 4]);
            const float av[4] = {af.x, af.y, af.z, af.w};
            float bv[TN];
#pragma unroll
            for (int j = 0; j < TN; j++) bv[j] = Bs[kk][tx * TN + j];
#pragma unroll
            for (int i = 0; i < 4; i++)
#pragma unroll
                for (int j = 0; j < TN; j++) c[i][j] = fmaf(av[i], bv[j], c[i][j]);
        }
        __syncthreads();
    }

#pragma unroll
    for (int i = 0; i < 4; i++) {
        long row = m0 + ty * 4 + i;
        long id = 0;
        if (EMB) id = ldix(idxp, row, i64);
        float ev[TN];
        if (EMB && TN == 4) {   // vectorized gather: 4 consecutive cols
            long ebase = id * (long)embN + n0 + tx * 4;
            if (fbf) {
                bf16x4 e4 = *reinterpret_cast<const bf16x4*>((const unsigned short*)emb + ebase);
#pragma unroll
                for (int j = 0; j < 4; j++) ev[j] = bf2f((unsigned short)e4[j]);
            } else {
                float4 e4 = *reinterpret_cast<const float4*>((const float*)emb + ebase);
                ev[0] = e4.x; ev[1] = e4.y; ev[2] = e4.z; ev[3] = e4.w;
            }
        }
#pragma unroll
        for (int j = 0; j < TN; j++) {
            int col = n0 + tx * TN + j;
            float v = c[i][j];
            if (TANH) v = fast_tanh(v);
            if (EMB)  v *= (TN == 4) ? ev[j] : ldf(emb, id * (long)embN + col, fbf);
            Cout[row * (long)N + col] = v;
        }
    }
}

// ---------- fused kd|vd GEMM: kvd[M][64] = x @ [W_k; W_v]^T  (BM=16 -> 512 blocks) ----------
__global__ __launch_bounds__(256) void gemm_kv_kernel(
    const void* __restrict__ A, const void* __restrict__ Wk,
    const void* __restrict__ Wv, float* __restrict__ kvd,
    const int* __restrict__ flags)
{
    const int fbf = flags[0];
    __shared__ float As[32][20];   // [k][m], pitch 20 (80B, 16B-aligned rows)
    __shared__ float Bs[32][68];   // [k][n]

    const int tid = threadIdx.x;
    const long m0 = (long)blockIdx.x * 16;
    const int tx = tid & 63;       // n (wave-lane)
    const int ty = tid >> 6;       // m-group (wave-uniform -> As broadcast)

    float c[4] = {0.f, 0.f, 0.f, 0.f};

    for (int k0 = 0; k0 < C_; k0 += 32) {
        {   // stage A: 16 rows x 32 k, 2 elems/thread
            int i = tid >> 4;
            int j0 = (tid & 15) * 2;
            long base = (m0 + i) * (long)C_ + k0 + j0;
            if (fbf) {
                unsigned u = *reinterpret_cast<const unsigned*>((const unsigned short*)A + base);
                As[j0][i]     = bf2f((unsigned short)(u & 0xffffu));
                As[j0 + 1][i] = bf2f((unsigned short)(u >> 16));
            } else {
                float2 f = *reinterpret_cast<const float2*>((const float*)A + base);
                As[j0][i] = f.x; As[j0 + 1][i] = f.y;
            }
        }
        {   // stage B: 64 rows (0-31 = W_k, 32-63 = W_v) x 32 k, 8 elems/thread
            int n = tid >> 2;
            int j0 = (tid & 3) * 8;
            const void* Wp = (n < 32) ? Wk : Wv;
            int nr = (n < 32) ? n : (n - 32);
            long base = (long)nr * C_ + k0 + j0;
            if (fbf) {
                bf16x8 bv = *reinterpret_cast<const bf16x8*>((const unsigned short*)Wp + base);
#pragma unroll
                for (int jj = 0; jj < 8; jj++) Bs[j0 + jj][n] = bf2f((unsigned short)bv[jj]);
            } else {
                const float4* bp = reinterpret_cast<const float4*>((const float*)Wp + base);
                float4 f0 = bp[0], f1 = bp[1];
                Bs[j0 + 0][n] = f0.x; Bs[j0 + 1][n] = f0.y;
                Bs[j0 + 2][n] = f0.z; Bs[j0 + 3][n] = f0.w;
                Bs[j0 + 4][n] = f1.x; Bs[j0 + 5][n] = f1.y;
                Bs[j0 + 6][n] = f1.z; Bs[j0 + 7][n] = f1.w;
            }
        }
        __syncthreads();
#pragma unroll
        for (int kk = 0; kk < 32; kk++) {
            const float4 af = *reinterpret_cast<const float4*>(&As[kk][ty * 4]);
            const float bv = Bs[kk][tx];
            c[0] = fmaf(af.x, bv, c[0]);
            c[1] = fmaf(af.y, bv, c[1]);
            c[2] = fmaf(af.z, bv, c[2]);
            c[3] = fmaf(af.w, bv, c[3]);
        }
        __syncthreads();
    }
#pragma unroll
    for (int i = 0; i < 4; i++)
        kvd[(m0 + ty * 4 + i) * 64 + tx] = c[i];
}

// ---------- fused time-shift + LayerNorm ----------
template<int DIM>
__global__ __launch_bounds__(256) void shiftln_kernel(
    const float* __restrict__ src, void* __restrict__ dst, int dst_bf16,
    const void* __restrict__ xs, const void* __restrict__ g,
    const void* __restrict__ bb, const int* __restrict__ flags)
{
    const int fbf = flags[0];
    const long r = blockIdx.x;
    const int t = (int)(r % T_);
    const int tid = threadIdx.x;
    constexpr int PT = DIM / 256;
    float m[PT];
    float s1 = 0.0f, s2 = 0.0f;
#pragma unroll
    for (int j = 0; j < PT; j++) {
        int o = tid + 256 * j;
        float v  = src[r * DIM + o];
        float pv = (t > 0) ? src[(r - 1) * DIM + o] : 0.0f;
        float xv = ldf(xs, o, fbf);
        float mm = v + (pv - v) * xv;
        m[j] = mm;
        s1 += mm;
        s2 += mm * mm;
    }
#pragma unroll
    for (int off = 32; off > 0; off >>= 1) {
        s1 += __shfl_xor(s1, off);
        s2 += __shfl_xor(s2, off);
    }
    __shared__ float r1[4], r2[4];
    int w = tid >> 6;
    if ((tid & 63) == 0) { r1[w] = s1; r2[w] = s2; }
    __syncthreads();
    float t1 = r1[0] + r1[1] + r1[2] + r1[3];
    float t2 = r2[0] + r2[1] + r2[2] + r2[3];
    float mean = t1 / (float)DIM;
    float var  = t2 / (float)DIM - mean * mean;
    float rs = rsqrtf(var + EPSF);
#pragma unroll
    for (int j = 0; j < PT; j++) {
        int o = tid + 256 * j;
        float y = (m[j] - mean) * rs * ldf(g, o, fbf) + ldf(bb, o, fbf);
        if (dst_bf16) ((unsigned short*)dst)[r * DIM + o] = f2bf(y);
        else          ((float*)dst)[r * DIM + o] = y;
    }
}

// ---------- transpose v: vpak u32[8192][512] (bf16 pairs) -> vT bf16 [B][1024][2048] ----------
__global__ __launch_bounds__(256) void vtrans_kernel(
    const unsigned* __restrict__ vpak, unsigned short* __restrict__ vT)
{
    __shared__ unsigned tile[64][33];
    const int row0 = blockIdx.x * 64;      // global row in [0, 8192)
    const int c0   = blockIdx.y * 64;      // channel base
    const int tid = threadIdx.x;
    {
        int i = tid >> 2, jg = tid & 3;
        const unsigned* src = vpak + (long)(row0 + i) * 512 + (c0 >> 1) + jg * 8;
#pragma unroll
        for (int u = 0; u < 8; u++) tile[i][jg * 8 + u] = src[u];
    }
    __syncthreads();
    const int ch = tid >> 2;               // local channel 0..63
    const int tc = (tid & 3) * 16;
    __align__(16) unsigned short buf[16];
#pragma unroll
    for (int u = 0; u < 16; u++) {
        unsigned wv = tile[tc + u][ch >> 1];
        buf[u] = (ch & 1) ? (unsigned short)(wv >> 16) : (unsigned short)(wv & 0xffffu);
    }
    const int bb = row0 / T_;
    const int t0 = row0 % T_;
    unsigned short* dst = vT + ((long)bb * C_ + c0 + ch) * T_ + t0 + tc;
    *reinterpret_cast<uint4*>(dst)     = *reinterpret_cast<const uint4*>(&buf[0]);
    *reinterpret_cast<uint4*>(dst + 8) = *reinterpret_cast<const uint4*>(&buf[8]);
}

// ---------- MFMA flash attention, QBLK=32, uniform work chunks ----------
// Round-6 lesson: fixed 4-way split left block work 0..8 tiles -> occupancy
// decayed to 18% avg (light blocks drain, heavy tail at 1-2 blocks/CU).
// Now each block = (batch, q-tile tb, chunk of <=4 key-tiles): 288 chunks
// per batch (sum ceil((tb/2+1)/4)), grid 1152, all blocks ~equal work.
// Decode: x=bx&7 -> XCD lane (batch b=x>>1 pinned to XCDs {2b,2b+1});
// cc=(bx>>3)*2+(x&1) in [0,288) -> (tb, chunk j) via uniform scalar scan.
// Chunk j covers tiles [4j, min(4j+4,nt)). Unnormalized O atomicAdd into
// pre-zeroed out; den -> denw[row][j]; normalize sums valid chunks only.
__global__ __launch_bounds__(256, 2) void attn_kernel(
    const unsigned short* __restrict__ q,   // bf16 [B*T][256]
    const unsigned short* __restrict__ k,   // bf16 [B*T][256]
    const unsigned short* __restrict__ vT,  // bf16 [B][1024][2048]
    float* __restrict__ out,                // pre-zeroed, atomic accumulate
    float* __restrict__ denw)               // [8192][8]
{
    __shared__ unsigned short qs[32 * 264];    // 16.5 KB
    __shared__ unsigned short ps[2][32 * 72];  // 9 KB, double-buffered
    __shared__ float dls[4][32];

    const int tid  = threadIdx.x;
    const int w    = tid >> 6;
    const int l    = tid & 63;
    const int l15  = l & 15;
    const int quad = l >> 4;

    const int bx = blockIdx.x;
    const int x  = bx & 7;
    const int b  = x >> 1;
    int cc = (bx >> 3) * 2 + (x & 1);      // chunk id in [0, 288)

    // uniform scan: find q-tile tb and local chunk j
    int tb = 0;
    for (; tb < 64; tb++) {
        int nch = (((tb >> 1) + 1) + 3) >> 2;
        if (cc < nch) break;
        cc -= nch;
    }
    const int jchunk = cc;
    const int t0 = tb * 32;
    const int nt = (tb >> 1) + 1;
    const int ts = jchunk * 4;
    const int te = (ts + 4 < nt) ? (ts + 4) : nt;

    // stage Q tile once: 32 rows x 256 shorts
    {
        int row = tid >> 3, seg = tid & 7;
        const unsigned short* src = q + ((long)b * T_ + t0 + row) * QD + seg * 32;
        unsigned short* dst = qs + row * 264 + seg * 32;
#pragma unroll
        for (int u = 0; u < 4; u++)
            *reinterpret_cast<bf16x8*>(dst + u * 8) =
                *reinterpret_cast<const bf16x8*>(src + u * 8);
    }
    __syncthreads();

    f32x4 acc[2][16];
#pragma unroll
    for (int mi = 0; mi < 2; mi++)
#pragma unroll
        for (int jt = 0; jt < 16; jt++) acc[mi][jt] = (f32x4){0.f, 0.f, 0.f, 0.f};
    float den[2][4] = {{0.f, 0.f, 0.f, 0.f}, {0.f, 0.f, 0.f, 0.f}};

    const unsigned short* vbase =
        vT + ((long)b * C_ + w * 256 + l15) * T_ + quad * 8;
    const unsigned short* kbase =
        k + ((long)b * T_ + w * 16 + l15) * QD + quad * 8;

    for (int tile = ts; tile < te; tile++) {
        const int kt0 = tile * 64;

        // K frags first (retire first in vm queue -> QK waits only on these)
        const unsigned short* kr = kbase + (long)kt0 * QD;
        bf16x8 kb[8];
#pragma unroll
        for (int ii = 0; ii < 8; ii++)
            kb[ii] = *reinterpret_cast<const bf16x8*>(kr + ii * 32);

        // V half-0 prefetch
        const unsigned short* vb = vbase + kt0;
        bf16x8 v0[16];
#pragma unroll
        for (int jt = 0; jt < 16; jt++)
            v0[jt] = *reinterpret_cast<const bf16x8*>(vb + (long)jt * 16 * T_);

        // QK^T: 2 q-frags x 8 k-chunks
        f32x4 s0 = (f32x4){0.f, 0.f, 0.f, 0.f};
        f32x4 s1 = (f32x4){0.f, 0.f, 0.f, 0.f};
        {
            const unsigned short* qb = qs + l15 * 264 + quad * 8;
#pragma unroll
            for (int ii = 0; ii < 8; ii++) {
                bf16x8 qa0 = *reinterpret_cast<const bf16x8*>(qb + ii * 32);
                bf16x8 qa1 = *reinterpret_cast<const bf16x8*>(qb + 16 * 264 + ii * 32);
                s0 = __builtin_amdgcn_mfma_f32_16x16x32_bf16(qa0, kb[ii], s0, 0, 0, 0);
                s1 = __builtin_amdgcn_mfma_f32_16x16x32_bf16(qa1, kb[ii], s1, 0, 0, 0);
            }
        }

        // softmax weights for both q-frags
        const int key = kt0 + w * 16 + l15;
        float wv[2][4];
#pragma unroll
        for (int mi = 0; mi < 2; mi++) {
#pragma unroll
            for (int rr = 0; rr < 4; rr++) {
                float sv = mi ? s1[rr] : s0[rr];
                int qrow = t0 + mi * 16 + quad * 4 + rr;
                float e = __expf(CAPS * fast_tanh(sv * INV_SS));
                e = (key <= qrow) ? e : 0.0f;
                wv[mi][rr] = bf2f(f2bf(e));     // round as PV will see it
            }
            float d0 = wv[mi][0], d1 = wv[mi][1], d2 = wv[mi][2], d3 = wv[mi][3];
#pragma unroll
            for (int off = 1; off < 16; off <<= 1) {
                d0 += __shfl_xor(d0, off);
                d1 += __shfl_xor(d1, off);
                d2 += __shfl_xor(d2, off);
                d3 += __shfl_xor(d3, off);
            }
            den[mi][0] += d0; den[mi][1] += d1; den[mi][2] += d2; den[mi][3] += d3;
        }

        // write P (bf16, A-layout rows), double-buffered
        unsigned short* psb = ps[tile & 1];
#pragma unroll
        for (int mi = 0; mi < 2; mi++)
#pragma unroll
            for (int rr = 0; rr < 4; rr++)
                psb[(mi * 16 + quad * 4 + rr) * 72 + w * 16 + l15] = f2bf(wv[mi][rr]);
        __syncthreads();   // one barrier/tile (dbuf covers W-A-R)

        // V half-1 (hides under PV half-0)
        bf16x8 v1[16];
#pragma unroll
        for (int jt = 0; jt < 16; jt++)
            v1[jt] = *reinterpret_cast<const bf16x8*>(vb + (long)jt * 16 * T_ + 32);

        // PV: 2 q-frags x 16 ch-frags x 2 k-halves
        {
            const unsigned short* pb = psb + l15 * 72 + quad * 8;
            bf16x8 pa00 = *reinterpret_cast<const bf16x8*>(pb);
            bf16x8 pa10 = *reinterpret_cast<const bf16x8*>(pb + 16 * 72);
#pragma unroll
            for (int jt = 0; jt < 16; jt++) {
                acc[0][jt] = __builtin_amdgcn_mfma_f32_16x16x32_bf16(pa00, v0[jt], acc[0][jt], 0, 0, 0);
                acc[1][jt] = __builtin_amdgcn_mfma_f32_16x16x32_bf16(pa10, v0[jt], acc[1][jt], 0, 0, 0);
            }
            bf16x8 pa01 = *reinterpret_cast<const bf16x8*>(pb + 32);
            bf16x8 pa11 = *reinterpret_cast<const bf16x8*>(pb + 16 * 72 + 32);
#pragma unroll
            for (int jt = 0; jt < 16; jt++) {
                acc[0][jt] = __builtin_amdgcn_mfma_f32_16x16x32_bf16(pa01, v1[jt], acc[0][jt], 0, 0, 0);
                acc[1][jt] = __builtin_amdgcn_mfma_f32_16x16x32_bf16(pa11, v1[jt], acc[1][jt], 0, 0, 0);
            }
        }
    }

    // combine denominators across waves; write per-chunk den
    if (l15 == 0) {
#pragma unroll
        for (int mi = 0; mi < 2; mi++)
#pragma unroll
            for (int rr = 0; rr < 4; rr++)
                dls[w][mi * 16 + quad * 4 + rr] = den[mi][rr];
    }
    __syncthreads();
    if (w == 0 && l15 == 0) {
#pragma unroll
        for (int mi = 0; mi < 2; mi++)
#pragma unroll
            for (int rr = 0; rr < 4; rr++) {
                int qr = mi * 16 + quad * 4 + rr;
                float d = dls[0][qr] + dls[1][qr] + dls[2][qr] + dls[3][qr];
                denw[((long)b * T_ + t0 + qr) * 8 + jchunk] = d;
            }
    }

    // atomic-accumulate UNNORMALIZED acc into out
    {
        float* ob = out + ((long)b * T_ + t0) * C_ + w * 256 + l15;
#pragma unroll
        for (int mi = 0; mi < 2; mi++)
#pragma unroll
            for (int jt = 0; jt < 16; jt++)
#pragma unroll
                for (int rr = 0; rr < 4; rr++)
                    atomicAdd(&ob[(long)(mi * 16 + quad * 4 + rr) * C_ + jt * 16],
                              acc[mi][jt][rr]);
    }
}

// ---------- normalize: out[row] /= sum(denw[row][0..nchunks)) ----------
__global__ __launch_bounds__(256) void normalize_kernel(
    float* __restrict__ out, const float* __restrict__ denw)
{
    const long row = blockIdx.x;
    const int t  = (int)(row % T_);
    const int tb = t >> 5;
    const int nt = (tb >> 1) + 1;
    const int nch = (nt + 3) >> 2;          // valid chunk slots for this row
    float dsum = 0.0f;
    for (int j = 0; j < nch; j++) dsum += denw[row * 8 + j];
    const float inv = 1.0f / dsum;
    const int c = threadIdx.x * 4;
    float4 o = *reinterpret_cast<const float4*>(out + row * C_ + c);
    o.x *= inv; o.y *= inv; o.z *= inv; o.w *= inv;
    *reinterpret_cast<float4*>(out + row * C_ + c) = o;
}

// ---------- launch ----------
extern "C" void kernel_launch(void* const* d_in, const int* in_sizes, int n_in,
                              void* d_out, int out_size, void* d_ws, size_t ws_size,
                              hipStream_t stream) {
    const void* x       = d_in[0];
    const void* idx     = d_in[1];
    const void* W_qq    = d_in[2];
    const void* W_k     = d_in[3];
    const void* W_kup   = d_in[4];
    const void* W_v     = d_in[5];
    const void* W_vup   = d_in[6];
    const void* k_emb   = d_in[7];
    const void* v_emb   = d_in[8];
    const void* x_q     = d_in[9];
    const void* x_k     = d_in[10];
    const void* x_v     = d_in[11];
    const void* g_q     = d_in[12];
    const void* b_q     = d_in[13];
    const void* g_k     = d_in[14];
    const void* b_k     = d_in[15];
    const void* g_v     = d_in[16];
    const void* b_v     = d_in[17];

    char* p = (char*)d_ws;
    int*   flags = (int*)p;            p += 256;
    float* qraw  = (float*)p;          p += (size_t)NR * QD * 4;       // 8 MB
    float* kvd   = (float*)p;          p += (size_t)NR * 64 * 4;       // 2 MB (kd|vd packed)
    float* kraw  = (float*)p;          p += (size_t)NR * QD * 4;       // 8 MB
    float* vraw  = (float*)p;          p += (size_t)NR * C_ * 4;       // 32 MB
    unsigned short* qf = (unsigned short*)p;  p += (size_t)NR * QD * 2; // 4 MB
    unsigned short* kf = (unsigned short*)p;  p += (size_t)NR * QD * 2; // 4 MB
    unsigned* vpak = (unsigned*)p;     p += (size_t)NR * (C_ / 2) * 4; // 16 MB
    unsigned short* vT = (unsigned short*)vraw;  // alias: vraw dead before vtrans
    // denw lives past vT's 16 MB (vT uses only first 16 MB of vraw's 32 MB);
    // written only by attn (after the vraw GEMM), valid slots summed by row.
    float* denw  = (float*)((char*)vraw + (size_t)16 * 1024 * 1024);   // 256 KB

    detect_kernel<<<1, 256, 0, stream>>>(x, idx, flags);
    zero_kernel<<<NR, 256, 0, stream>>>((float*)d_out);

    gemm_kernel<64, 0, 0><<<dim3(NR / 64, QD / 64), 256, 0, stream>>>(
        x, W_qq, nullptr, nullptr, qraw, NR, C_, QD, 0, 1, flags, C_);
    gemm_kv_kernel<<<NR / 16, 256, 0, stream>>>(x, W_k, W_v, kvd, flags);
    gemm_kernel<64, 0, 1><<<dim3(NR / 64, QD / 64), 256, 0, stream>>>(
        kvd, W_kup, k_emb, idx, kraw, NR, KVD, QD, QD, 0, flags, 64);
    gemm_kernel<64, 1, 1><<<dim3(NR / 64, C_ / 64), 256, 0, stream>>>(
        (const float*)kvd + 32, W_vup, v_emb, idx, vraw, NR, KVD, C_, C_, 0, flags, 64);

    shiftln_kernel<QD><<<NR, 256, 0, stream>>>(qraw, qf, 1, x_q, g_q, b_q, flags);
    shiftln_kernel<QD><<<NR, 256, 0, stream>>>(kraw, kf, 1, x_k, g_k, b_k, flags);
    shiftln_kernel<C_><<<NR, 256, 0, stream>>>(vraw, vpak, 1, x_v, g_v, b_v, flags);

    vtrans_kernel<<<dim3(NR / 64, C_ / 64), 256, 0, stream>>>(vpak, vT);

    attn_kernel<<<1152, 256, 0, stream>>>(qf, kf, vT, (float*)d_out, denw);
    normalize_kernel<<<NR, 256, 0, stream>>>((float*)d_out, denw);
}

// Round 8
// 671.053 us; speedup vs baseline: 1.0368x; 1.0368x over previous
//
#include <hip/hip_runtime.h>

#define B_   4
#define T_   2048
#define C_   1024
#define QD   256
#define KVD  32
#define NR   (B_*T_)          // 8192 rows
#define EPSF 1e-5f
#define CAPS 64.0f
#define INV_SS (1.0f/1024.0f)

typedef __attribute__((ext_vector_type(8))) short bf16x8;
typedef __attribute__((ext_vector_type(4))) short bf16x4;
typedef __attribute__((ext_vector_type(4))) float f32x4;

// ---------- dtype helpers (runtime-flagged) ----------
__device__ __forceinline__ float bf2f(unsigned short h) {
    return __uint_as_float(((unsigned)h) << 16);
}
__device__ __forceinline__ unsigned short f2bf(float f) {
    unsigned u = __float_as_uint(f);
    u = u + 0x7fffu + ((u >> 16) & 1u);   // round-to-nearest-even
    return (unsigned short)(u >> 16);
}
__device__ __forceinline__ float ldf(const void* p, long i, int isbf) {
    return isbf ? bf2f(((const unsigned short*)p)[i]) : ((const float*)p)[i];
}
__device__ __forceinline__ long ldix(const void* p, long i, int is64) {
    return is64 ? (long)((const long long*)p)[i] : (long)((const int*)p)[i];
}
__device__ __forceinline__ float fast_tanh(float v) {
    float u = __expf(2.0f * v);          // overflow->inf->th=1; underflow->0->th=-1
    return 1.0f - 2.0f / (u + 1.0f);
}

// ---------- dtype detection ----------
__global__ void detect_kernel(const void* x, const void* idxp, int* flags) {
    __shared__ int cnt[2];
    int tid = threadIdx.x;
    if (tid < 2) cnt[tid] = 0;
    __syncthreads();
    int pl = 0;
    const unsigned short* u = (const unsigned short*)x;
    for (int r = 0; r < 2; r++) {
        long j = 2L * (((long)(tid * 2 + r) * 15013L) % 4000000L);
        unsigned short v = u[j];
        int e = (v >> 7) & 0xff;
        pl += (v == 0 || (e >= 100 && e <= 140)) ? 1 : 0;
    }
    atomicAdd(&cnt[0], pl);
    const unsigned* w = (const unsigned*)idxp;
    int z = (w[2 * tid + 1] == 0u) ? 1 : 0;
    atomicAdd(&cnt[1], z);
    __syncthreads();
    if (tid == 0) {
        flags[0] = (cnt[0] > 384) ? 1 : 0;   // float tensors are bf16
        flags[1] = (cnt[1] > 128) ? 1 : 0;   // idx is int64
    }
}

// ---------- zero the attention output (atomic-accumulate target) ----------
__global__ __launch_bounds__(256) void zero_kernel(float* __restrict__ out) {
    const long i = ((long)blockIdx.x * 256 + threadIdx.x) * 4;
    *reinterpret_cast<float4*>(out + i) = (float4){0.f, 0.f, 0.f, 0.f};
}

// ---------- MFMA GEMM (bf16 inputs only): C[M][N] = A[M][K] @ Wrows^T ----------
// Wrows n < nsplit from W, else from W2 (row n-nsplit). 64x64 tile, 4 waves;
// wave w covers cols [w*16,+16), 4 m-frags of 16 rows. A staged in LDS
// (attn-proven 264-pitch layout), W rows direct global->regs (L2-resident).
__global__ __launch_bounds__(256) void gemm_mfma_kernel(
    const unsigned short* __restrict__ A,
    const unsigned short* __restrict__ W,
    const unsigned short* __restrict__ W2,
    float* __restrict__ C, int N, int K, int nsplit,
    const int* __restrict__ flags)
{
    if (!flags[0]) return;                 // fp32 inputs -> VALU kernels handle it
    __shared__ unsigned short As[64 * 264];

    const int tid  = threadIdx.x;
    const int w    = tid >> 6;
    const int l    = tid & 63;
    const int l15  = l & 15;
    const int quad = l >> 4;

    const long m0 = (long)blockIdx.x * 64;
    const int  n  = blockIdx.y * 64 + w * 16 + l15;
    const unsigned short* Wrow =
        ((n < nsplit) ? (W + (long)n * K) : (W2 + (long)(n - nsplit) * K)) + quad * 8;

    f32x4 acc[4];
#pragma unroll
    for (int mi = 0; mi < 4; mi++) acc[mi] = (f32x4){0.f, 0.f, 0.f, 0.f};

    for (int k0 = 0; k0 < K; k0 += 256) {
        if (k0) __syncthreads();           // previous chunk reads done
        {   // stage A 64 rows x 256 k
            int row = tid >> 2, seg = tid & 3;
            const unsigned short* src = A + (m0 + row) * (long)K + k0 + seg * 64;
            unsigned short* dst = As + row * 264 + seg * 64;
#pragma unroll
            for (int u = 0; u < 8; u++)
                *reinterpret_cast<bf16x8*>(dst + u * 8) =
                    *reinterpret_cast<const bf16x8*>(src + u * 8);
        }
        __syncthreads();

        bf16x8 kb[8];
#pragma unroll
        for (int ii = 0; ii < 8; ii++)
            kb[ii] = *reinterpret_cast<const bf16x8*>(Wrow + k0 + ii * 32);

        const unsigned short* qb = As + l15 * 264 + quad * 8;
#pragma unroll
        for (int ii = 0; ii < 8; ii++)
#pragma unroll
            for (int mi = 0; mi < 4; mi++) {
                bf16x8 qa = *reinterpret_cast<const bf16x8*>(qb + mi * 16 * 264 + ii * 32);
                acc[mi] = __builtin_amdgcn_mfma_f32_16x16x32_bf16(qa, kb[ii], acc[mi], 0, 0, 0);
            }
    }

#pragma unroll
    for (int mi = 0; mi < 4; mi++)
#pragma unroll
        for (int rr = 0; rr < 4; rr++)
            C[(m0 + mi * 16 + quad * 4 + rr) * (long)N + n] = acc[mi][rr];
}

// ---------- tiled GEMM: C[M,N] = act(A[M,K] @ W[N,K]^T) (* emb gather) ----------
template<int BN, int TANH, int EMB>
__global__ __launch_bounds__(256) void gemm_kernel(
    const void* __restrict__ A, const void* __restrict__ W,
    const void* __restrict__ emb, const void* __restrict__ idxp,
    float* __restrict__ Cout, int M, int K, int N, int embN, int amode,
    const int* __restrict__ flags, int lda, int skipbf)
{
    const int fbf = flags[0];
    if (skipbf && fbf) return;             // bf16 path handled by gemm_mfma_kernel
    const int abf = amode ? fbf : 0;
    const int i64 = flags[1];

    __shared__ float As[32][68];
    __shared__ float Bs[32][BN + 4];

    const int tid = threadIdx.x;
    const long m0 = (long)blockIdx.x * 64;
    const int  n0 = blockIdx.y * BN;
    constexpr int TN = (BN == 64) ? 4 : 2;
    const int tx = tid & 15;
    const int ty = tid >> 4;

    float c[4][TN];
#pragma unroll
    for (int i = 0; i < 4; i++)
#pragma unroll
        for (int j = 0; j < TN; j++) c[i][j] = 0.0f;

    for (int k0 = 0; k0 < K; k0 += 32) {
        {
            int i = tid >> 2;
            int j0 = (tid & 3) * 8;
            long base = (m0 + i) * (long)lda + k0 + j0;
            if (abf) {
                bf16x8 av = *reinterpret_cast<const bf16x8*>((const unsigned short*)A + base);
#pragma unroll
                for (int jj = 0; jj < 8; jj++) As[j0 + jj][i] = bf2f((unsigned short)av[jj]);
            } else {
                const float4* ap = reinterpret_cast<const float4*>((const float*)A + base);
                float4 f0 = ap[0], f1 = ap[1];
                As[j0 + 0][i] = f0.x; As[j0 + 1][i] = f0.y;
                As[j0 + 2][i] = f0.z; As[j0 + 3][i] = f0.w;
                As[j0 + 4][i] = f1.x; As[j0 + 5][i] = f1.y;
                As[j0 + 6][i] = f1.z; As[j0 + 7][i] = f1.w;
            }
        }
        if (BN == 64) {
            int n = tid >> 2;
            int j0 = (tid & 3) * 8;
            long base = (long)(n0 + n) * K + k0 + j0;
            if (fbf) {
                bf16x8 bv = *reinterpret_cast<const bf16x8*>((const unsigned short*)W + base);
#pragma unroll
                for (int jj = 0; jj < 8; jj++) Bs[j0 + jj][n] = bf2f((unsigned short)bv[jj]);
            } else {
                const float4* bp = reinterpret_cast<const float4*>((const float*)W + base);
                float4 f0 = bp[0], f1 = bp[1];
                Bs[j0 + 0][n] = f0.x; Bs[j0 + 1][n] = f0.y;
                Bs[j0 + 2][n] = f0.z; Bs[j0 + 3][n] = f0.w;
                Bs[j0 + 4][n] = f1.x; Bs[j0 + 5][n] = f1.y;
                Bs[j0 + 6][n] = f1.z; Bs[j0 + 7][n] = f1.w;
            }
        } else {
            int n = tid >> 3;
            int j0 = (tid & 7) * 4;
            long base = (long)(n0 + n) * K + k0 + j0;
            if (fbf) {
                bf16x4 bv = *reinterpret_cast<const bf16x4*>((const unsigned short*)W + base);
#pragma unroll
                for (int jj = 0; jj < 4; jj++) Bs[j0 + jj][n] = bf2f((unsigned short)bv[jj]);
            } else {
                float4 f0 = *reinterpret_cast<const float4*>((const float*)W + base);
                Bs[j0 + 0][n] = f0.x; Bs[j0 + 1][n] = f0.y;
                Bs[j0 + 2][n] = f0.z; Bs[j0 + 3][n] = f0.w;
            }
        }
        __syncthreads();
#pragma unroll
        for (int kk = 0; kk < 32; kk++) {
            const float4 af = *reinterpret_cast<const float4*>(&As[kk][ty * 4]);
            const float av[4] = {af.x, af.y, af.z, af.w};
            float bv[TN];
#pragma unroll
            for (int j = 0; j < TN; j++) bv[j] = Bs[kk][tx * TN + j];
#pragma unroll
            for (int i = 0; i < 4; i++)
#pragma unroll
                for (int j = 0; j < TN; j++) c[i][j] = fmaf(av[i], bv[j], c[i][j]);
        }
        __syncthreads();
    }

#pragma unroll
    for (int i = 0; i < 4; i++) {
        long row = m0 + ty * 4 + i;
        long id = 0;
        if (EMB) id = ldix(idxp, row, i64);
        float ev[TN];
        if (EMB && TN == 4) {   // vectorized gather: 4 consecutive cols
            long ebase = id * (long)embN + n0 + tx * 4;
            if (fbf) {
                bf16x4 e4 = *reinterpret_cast<const bf16x4*>((const unsigned short*)emb + ebase);
#pragma unroll
                for (int j = 0; j < 4; j++) ev[j] = bf2f((unsigned short)e4[j]);
            } else {
                float4 e4 = *reinterpret_cast<const float4*>((const float*)emb + ebase);
                ev[0] = e4.x; ev[1] = e4.y; ev[2] = e4.z; ev[3] = e4.w;
            }
        }
#pragma unroll
        for (int j = 0; j < TN; j++) {
            int col = n0 + tx * TN + j;
            float v = c[i][j];
            if (TANH) v = fast_tanh(v);
            if (EMB)  v *= (TN == 4) ? ev[j] : ldf(emb, id * (long)embN + col, fbf);
            Cout[row * (long)N + col] = v;
        }
    }
}

// ---------- fused kd|vd GEMM (fp32 fallback): kvd[M][64] = x @ [W_k; W_v]^T ----------
__global__ __launch_bounds__(256) void gemm_kv_kernel(
    const void* __restrict__ A, const void* __restrict__ Wk,
    const void* __restrict__ Wv, float* __restrict__ kvd,
    const int* __restrict__ flags)
{
    const int fbf = flags[0];
    if (fbf) return;                       // bf16 path handled by gemm_mfma_kernel
    __shared__ float As[32][20];
    __shared__ float Bs[32][68];

    const int tid = threadIdx.x;
    const long m0 = (long)blockIdx.x * 16;
    const int tx = tid & 63;
    const int ty = tid >> 6;

    float c[4] = {0.f, 0.f, 0.f, 0.f};

    for (int k0 = 0; k0 < C_; k0 += 32) {
        {
            int i = tid >> 4;
            int j0 = (tid & 15) * 2;
            long base = (m0 + i) * (long)C_ + k0 + j0;
            float2 f = *reinterpret_cast<const float2*>((const float*)A + base);
            As[j0][i] = f.x; As[j0 + 1][i] = f.y;
        }
        {
            int n = tid >> 2;
            int j0 = (tid & 3) * 8;
            const void* Wp = (n < 32) ? Wk : Wv;
            int nr = (n < 32) ? n : (n - 32);
            long base = (long)nr * C_ + k0 + j0;
            const float4* bp = reinterpret_cast<const float4*>((const float*)Wp + base);
            float4 f0 = bp[0], f1 = bp[1];
            Bs[j0 + 0][n] = f0.x; Bs[j0 + 1][n] = f0.y;
            Bs[j0 + 2][n] = f0.z; Bs[j0 + 3][n] = f0.w;
            Bs[j0 + 4][n] = f1.x; Bs[j0 + 5][n] = f1.y;
            Bs[j0 + 6][n] = f1.z; Bs[j0 + 7][n] = f1.w;
        }
        __syncthreads();
#pragma unroll
        for (int kk = 0; kk < 32; kk++) {
            const float4 af = *reinterpret_cast<const float4*>(&As[kk][ty * 4]);
            const float bv = Bs[kk][tx];
            c[0] = fmaf(af.x, bv, c[0]);
            c[1] = fmaf(af.y, bv, c[1]);
            c[2] = fmaf(af.z, bv, c[2]);
            c[3] = fmaf(af.w, bv, c[3]);
        }
        __syncthreads();
    }
#pragma unroll
    for (int i = 0; i < 4; i++)
        kvd[(m0 + ty * 4 + i) * 64 + tx] = c[i];
}

// ---------- fused time-shift + LayerNorm ----------
template<int DIM>
__global__ __launch_bounds__(256) void shiftln_kernel(
    const float* __restrict__ src, void* __restrict__ dst, int dst_bf16,
    const void* __restrict__ xs, const void* __restrict__ g,
    const void* __restrict__ bb, const int* __restrict__ flags)
{
    const int fbf = flags[0];
    const long r = blockIdx.x;
    const int t = (int)(r % T_);
    const int tid = threadIdx.x;
    constexpr int PT = DIM / 256;
    float m[PT];
    float s1 = 0.0f, s2 = 0.0f;
#pragma unroll
    for (int j = 0; j < PT; j++) {
        int o = tid + 256 * j;
        float v  = src[r * DIM + o];
        float pv = (t > 0) ? src[(r - 1) * DIM + o] : 0.0f;
        float xv = ldf(xs, o, fbf);
        float mm = v + (pv - v) * xv;
        m[j] = mm;
        s1 += mm;
        s2 += mm * mm;
    }
#pragma unroll
    for (int off = 32; off > 0; off >>= 1) {
        s1 += __shfl_xor(s1, off);
        s2 += __shfl_xor(s2, off);
    }
    __shared__ float r1[4], r2[4];
    int w = tid >> 6;
    if ((tid & 63) == 0) { r1[w] = s1; r2[w] = s2; }
    __syncthreads();
    float t1 = r1[0] + r1[1] + r1[2] + r1[3];
    float t2 = r2[0] + r2[1] + r2[2] + r2[3];
    float mean = t1 / (float)DIM;
    float var  = t2 / (float)DIM - mean * mean;
    float rs = rsqrtf(var + EPSF);
#pragma unroll
    for (int j = 0; j < PT; j++) {
        int o = tid + 256 * j;
        float y = (m[j] - mean) * rs * ldf(g, o, fbf) + ldf(bb, o, fbf);
        if (dst_bf16) ((unsigned short*)dst)[r * DIM + o] = f2bf(y);
        else          ((float*)dst)[r * DIM + o] = y;
    }
}

// ---------- transpose v: vpak u32[8192][512] (bf16 pairs) -> vT bf16 [B][1024][2048] ----------
__global__ __launch_bounds__(256) void vtrans_kernel(
    const unsigned* __restrict__ vpak, unsigned short* __restrict__ vT)
{
    __shared__ unsigned tile[64][33];
    const int row0 = blockIdx.x * 64;      // global row in [0, 8192)
    const int c0   = blockIdx.y * 64;      // channel base
    const int tid = threadIdx.x;
    {
        int i = tid >> 2, jg = tid & 3;
        const unsigned* src = vpak + (long)(row0 + i) * 512 + (c0 >> 1) + jg * 8;
#pragma unroll
        for (int u = 0; u < 8; u++) tile[i][jg * 8 + u] = src[u];
    }
    __syncthreads();
    const int ch = tid >> 2;               // local channel 0..63
    const int tc = (tid & 3) * 16;
    __align__(16) unsigned short buf[16];
#pragma unroll
    for (int u = 0; u < 16; u++) {
        unsigned wv = tile[tc + u][ch >> 1];
        buf[u] = (ch & 1) ? (unsigned short)(wv >> 16) : (unsigned short)(wv & 0xffffu);
    }
    const int bb = row0 / T_;
    const int t0 = row0 % T_;
    unsigned short* dst = vT + ((long)bb * C_ + c0 + ch) * T_ + t0 + tc;
    *reinterpret_cast<uint4*>(dst)     = *reinterpret_cast<const uint4*>(&buf[0]);
    *reinterpret_cast<uint4*>(dst + 8) = *reinterpret_cast<const uint4*>(&buf[8]);
}

// ---------- MFMA flash attention, QBLK=32, 4-way key-split (round-6 best) ----------
__global__ __launch_bounds__(256, 2) void attn_kernel(
    const unsigned short* __restrict__ q,   // bf16 [B*T][256]
    const unsigned short* __restrict__ k,   // bf16 [B*T][256]
    const unsigned short* __restrict__ vT,  // bf16 [B][1024][2048]
    float* __restrict__ out,                // pre-zeroed, atomic accumulate
    float* __restrict__ denw)               // [8192][4]
{
    __shared__ unsigned short qs[32 * 264];    // 16.5 KB
    __shared__ unsigned short ps[2][32 * 72];  // 9 KB, double-buffered
    __shared__ float dls[4][32];

    const int tid  = threadIdx.x;
    const int w    = tid >> 6;
    const int l    = tid & 63;
    const int l15  = l & 15;
    const int quad = l >> 4;

    const int bx    = blockIdx.x;
    const int g     = bx >> 3;
    const int x     = bx & 7;
    const int b     = x >> 1;
    const int split = ((x & 1) << 1) | (g & 1);
    const int tb    = 63 - (g >> 1);
    const int t0    = tb * 32;

    const int nt = t0 / 64 + 1;
    const int ts = (nt * split) >> 2;
    const int te = (nt * (split + 1)) >> 2;

    // stage Q tile once: 32 rows x 256 shorts
    {
        int row = tid >> 3, seg = tid & 7;
        const unsigned short* src = q + ((long)b * T_ + t0 + row) * QD + seg * 32;
        unsigned short* dst = qs + row * 264 + seg * 32;
#pragma unroll
        for (int u = 0; u < 4; u++)
            *reinterpret_cast<bf16x8*>(dst + u * 8) =
                *reinterpret_cast<const bf16x8*>(src + u * 8);
    }
    __syncthreads();

    f32x4 acc[2][16];
#pragma unroll
    for (int mi = 0; mi < 2; mi++)
#pragma unroll
        for (int jt = 0; jt < 16; jt++) acc[mi][jt] = (f32x4){0.f, 0.f, 0.f, 0.f};
    float den[2][4] = {{0.f, 0.f, 0.f, 0.f}, {0.f, 0.f, 0.f, 0.f}};

    const unsigned short* vbase =
        vT + ((long)b * C_ + w * 256 + l15) * T_ + quad * 8;
    const unsigned short* kbase =
        k + ((long)b * T_ + w * 16 + l15) * QD + quad * 8;

    for (int tile = ts; tile < te; tile++) {
        const int kt0 = tile * 64;

        // K frags first (retire first in vm queue -> QK waits only on these)
        const unsigned short* kr = kbase + (long)kt0 * QD;
        bf16x8 kb[8];
#pragma unroll
        for (int ii = 0; ii < 8; ii++)
            kb[ii] = *reinterpret_cast<const bf16x8*>(kr + ii * 32);

        // V half-0 prefetch
        const unsigned short* vb = vbase + kt0;
        bf16x8 v0[16];
#pragma unroll
        for (int jt = 0; jt < 16; jt++)
            v0[jt] = *reinterpret_cast<const bf16x8*>(vb + (long)jt * 16 * T_);

        // QK^T: 2 q-frags x 8 k-chunks
        f32x4 s0 = (f32x4){0.f, 0.f, 0.f, 0.f};
        f32x4 s1 = (f32x4){0.f, 0.f, 0.f, 0.f};
        {
            const unsigned short* qb = qs + l15 * 264 + quad * 8;
#pragma unroll
            for (int ii = 0; ii < 8; ii++) {
                bf16x8 qa0 = *reinterpret_cast<const bf16x8*>(qb + ii * 32);
                bf16x8 qa1 = *reinterpret_cast<const bf16x8*>(qb + 16 * 264 + ii * 32);
                s0 = __builtin_amdgcn_mfma_f32_16x16x32_bf16(qa0, kb[ii], s0, 0, 0, 0);
                s1 = __builtin_amdgcn_mfma_f32_16x16x32_bf16(qa1, kb[ii], s1, 0, 0, 0);
            }
        }

        // softmax weights for both q-frags
        const int key = kt0 + w * 16 + l15;
        float wv[2][4];
#pragma unroll
        for (int mi = 0; mi < 2; mi++) {
#pragma unroll
            for (int rr = 0; rr < 4; rr++) {
                float sv = mi ? s1[rr] : s0[rr];
                int qrow = t0 + mi * 16 + quad * 4 + rr;
                float e = __expf(CAPS * fast_tanh(sv * INV_SS));
                e = (key <= qrow) ? e : 0.0f;
                wv[mi][rr] = bf2f(f2bf(e));     // round as PV will see it
            }
            float d0 = wv[mi][0], d1 = wv[mi][1], d2 = wv[mi][2], d3 = wv[mi][3];
#pragma unroll
            for (int off = 1; off < 16; off <<= 1) {
                d0 += __shfl_xor(d0, off);
                d1 += __shfl_xor(d1, off);
                d2 += __shfl_xor(d2, off);
                d3 += __shfl_xor(d3, off);
            }
            den[mi][0] += d0; den[mi][1] += d1; den[mi][2] += d2; den[mi][3] += d3;
        }

        // write P (bf16, A-layout rows), double-buffered
        unsigned short* psb = ps[tile & 1];
#pragma unroll
        for (int mi = 0; mi < 2; mi++)
#pragma unroll
            for (int rr = 0; rr < 4; rr++)
                psb[(mi * 16 + quad * 4 + rr) * 72 + w * 16 + l15] = f2bf(wv[mi][rr]);
        __syncthreads();   // one barrier/tile (dbuf covers W-A-R)

        // V half-1 (hides under PV half-0)
        bf16x8 v1[16];
#pragma unroll
        for (int jt = 0; jt < 16; jt++)
            v1[jt] = *reinterpret_cast<const bf16x8*>(vb + (long)jt * 16 * T_ + 32);

        // PV: 2 q-frags x 16 ch-frags x 2 k-halves
        {
            const unsigned short* pb = psb + l15 * 72 + quad * 8;
            bf16x8 pa00 = *reinterpret_cast<const bf16x8*>(pb);
            bf16x8 pa10 = *reinterpret_cast<const bf16x8*>(pb + 16 * 72);
#pragma unroll
            for (int jt = 0; jt < 16; jt++) {
                acc[0][jt] = __builtin_amdgcn_mfma_f32_16x16x32_bf16(pa00, v0[jt], acc[0][jt], 0, 0, 0);
                acc[1][jt] = __builtin_amdgcn_mfma_f32_16x16x32_bf16(pa10, v0[jt], acc[1][jt], 0, 0, 0);
            }
            bf16x8 pa01 = *reinterpret_cast<const bf16x8*>(pb + 32);
            bf16x8 pa11 = *reinterpret_cast<const bf16x8*>(pb + 16 * 72 + 32);
#pragma unroll
            for (int jt = 0; jt < 16; jt++) {
                acc[0][jt] = __builtin_amdgcn_mfma_f32_16x16x32_bf16(pa01, v1[jt], acc[0][jt], 0, 0, 0);
                acc[1][jt] = __builtin_amdgcn_mfma_f32_16x16x32_bf16(pa11, v1[jt], acc[1][jt], 0, 0, 0);
            }
        }
    }

    // combine denominators across waves; write per-split den
    if (l15 == 0) {
#pragma unroll
        for (int mi = 0; mi < 2; mi++)
#pragma unroll
            for (int rr = 0; rr < 4; rr++)
                dls[w][mi * 16 + quad * 4 + rr] = den[mi][rr];
    }
    __syncthreads();
    if (w == 0 && l15 == 0) {
#pragma unroll
        for (int mi = 0; mi < 2; mi++)
#pragma unroll
            for (int rr = 0; rr < 4; rr++) {
                int qr = mi * 16 + quad * 4 + rr;
                float d = dls[0][qr] + dls[1][qr] + dls[2][qr] + dls[3][qr];
                denw[((long)b * T_ + t0 + qr) * 4 + split] = d;
            }
    }

    // atomic-accumulate UNNORMALIZED acc into out
    {
        float* ob = out + ((long)b * T_ + t0) * C_ + w * 256 + l15;
#pragma unroll
        for (int mi = 0; mi < 2; mi++)
#pragma unroll
            for (int jt = 0; jt < 16; jt++)
#pragma unroll
                for (int rr = 0; rr < 4; rr++)
                    atomicAdd(&ob[(long)(mi * 16 + quad * 4 + rr) * C_ + jt * 16],
                              acc[mi][jt][rr]);
    }
}

// ---------- normalize: out[row] /= sum(denw[row][0..3]) ----------
__global__ __launch_bounds__(256) void normalize_kernel(
    float* __restrict__ out, const float* __restrict__ denw)
{
    const long row = blockIdx.x;
    const float4 d = *reinterpret_cast<const float4*>(denw + row * 4);
    const float inv = 1.0f / (d.x + d.y + d.z + d.w);
    const int c = threadIdx.x * 4;
    float4 o = *reinterpret_cast<const float4*>(out + row * C_ + c);
    o.x *= inv; o.y *= inv; o.z *= inv; o.w *= inv;
    *reinterpret_cast<float4*>(out + row * C_ + c) = o;
}

// ---------- launch ----------
extern "C" void kernel_launch(void* const* d_in, const int* in_sizes, int n_in,
                              void* d_out, int out_size, void* d_ws, size_t ws_size,
                              hipStream_t stream) {
    const void* x       = d_in[0];
    const void* idx     = d_in[1];
    const void* W_qq    = d_in[2];
    const void* W_k     = d_in[3];
    const void* W_kup   = d_in[4];
    const void* W_v     = d_in[5];
    const void* W_vup   = d_in[6];
    const void* k_emb   = d_in[7];
    const void* v_emb   = d_in[8];
    const void* x_q     = d_in[9];
    const void* x_k     = d_in[10];
    const void* x_v     = d_in[11];
    const void* g_q     = d_in[12];
    const void* b_q     = d_in[13];
    const void* g_k     = d_in[14];
    const void* b_k     = d_in[15];
    const void* g_v     = d_in[16];
    const void* b_v     = d_in[17];

    char* p = (char*)d_ws;
    int*   flags = (int*)p;            p += 256;
    float* qraw  = (float*)p;          p += (size_t)NR * QD * 4;       // 8 MB
    float* kvd   = (float*)p;          p += (size_t)NR * 64 * 4;       // 2 MB (kd|vd packed)
    float* kraw  = (float*)p;          p += (size_t)NR * QD * 4;       // 8 MB
    float* vraw  = (float*)p;          p += (size_t)NR * C_ * 4;       // 32 MB
    unsigned short* qf = (unsigned short*)p;  p += (size_t)NR * QD * 2; // 4 MB
    unsigned short* kf = (unsigned short*)p;  p += (size_t)NR * QD * 2; // 4 MB
    unsigned* vpak = (unsigned*)p;     p += (size_t)NR * (C_ / 2) * 4; // 16 MB
    unsigned short* vT = (unsigned short*)vraw;  // alias: vraw dead before vtrans
    float* denw  = (float*)((char*)vraw + (size_t)16 * 1024 * 1024);   // 128 KB

    detect_kernel<<<1, 256, 0, stream>>>(x, idx, flags);
    zero_kernel<<<NR, 256, 0, stream>>>((float*)d_out);

    // qq GEMM: MFMA path (bf16) + VALU fallback (fp32); each early-exits on flag
    gemm_mfma_kernel<<<dim3(NR / 64, QD / 64), 256, 0, stream>>>(
        (const unsigned short*)x, (const unsigned short*)W_qq,
        (const unsigned short*)W_qq, qraw, QD, C_, QD, flags);
    gemm_kernel<64, 0, 0><<<dim3(NR / 64, QD / 64), 256, 0, stream>>>(
        x, W_qq, nullptr, nullptr, qraw, NR, C_, QD, 0, 1, flags, C_, 1);

    // kd|vd GEMM: MFMA (bf16, W_k rows 0-31 / W_v rows 32-63) + VALU fallback
    gemm_mfma_kernel<<<dim3(NR / 64, 1), 256, 0, stream>>>(
        (const unsigned short*)x, (const unsigned short*)W_k,
        (const unsigned short*)W_v, kvd, 64, C_, 32, flags);
    gemm_kv_kernel<<<NR / 16, 256, 0, stream>>>(x, W_k, W_v, kvd, flags);

    gemm_kernel<64, 0, 1><<<dim3(NR / 64, QD / 64), 256, 0, stream>>>(
        kvd, W_kup, k_emb, idx, kraw, NR, KVD, QD, QD, 0, flags, 64, 0);
    gemm_kernel<64, 1, 1><<<dim3(NR / 64, C_ / 64), 256, 0, stream>>>(
        (const float*)kvd + 32, W_vup, v_emb, idx, vraw, NR, KVD, C_, C_, 0, flags, 64, 0);

    shiftln_kernel<QD><<<NR, 256, 0, stream>>>(qraw, qf, 1, x_q, g_q, b_q, flags);
    shiftln_kernel<QD><<<NR, 256, 0, stream>>>(kraw, kf, 1, x_k, g_k, b_k, flags);
    shiftln_kernel<C_><<<NR, 256, 0, stream>>>(vraw, vpak, 1, x_v, g_v, b_v, flags);

    vtrans_kernel<<<dim3(NR / 64, C_ / 64), 256, 0, stream>>>(vpak, vT);

    attn_kernel<<<1024, 256, 0, stream>>>(qf, kf, vT, (float*)d_out, denw);
    normalize_kernel<<<NR, 256, 0, stream>>>((float*)d_out, denw);
}